// Round 3
// baseline (69.852 us; speedup 1.0000x reference)
//
#include <hip/hip_runtime.h>

#define NITER 25

// fp64 rcp via v_rcp_f64 + 2 Newton refinements (~1 ulp).
__device__ __forceinline__ double fast_rcp(double x) {
#if __has_builtin(__builtin_amdgcn_rcp)
    double r = __builtin_amdgcn_rcp(x);
    r = fma(fma(-x, r, 1.0), r, r);
    r = fma(fma(-x, r, 1.0), r, r);
    return r;
#else
    return 1.0 / x;
#endif
}

// fp32 rcp (v_rcp_f32, ~1 ulp) — only for fraction-to-boundary ratios.
__device__ __forceinline__ float fast_rcpf(float x) {
#if __has_builtin(__builtin_amdgcn_rcpf)
    return __builtin_amdgcn_rcpf(x);
#else
    return 1.0f / x;
#endif
}

// Per-thread fp64 interior-point LCP, 25 iterations, TWO PROBLEMS PER THREAD.
//
// Why 2/thread: B=131072 -> 2048 waves = 2/SIMD fixed; measured ~2842
// cyc/iter vs ~1190 issue-bound -> latency-stalled at ~42% issue util.
// Folding 2 independent problems into one wave (1024 waves = 1/SIMD, same
// total work) doubles per-wave ILP: two independent DAGs interleave and
// cover fp64 latency. Per-problem arithmetic is UNCHANGED (bit-identical).
//
// Per-problem solve (validated rounds 0-2): 4x4 Schur, denominator-cleared
// (row i scaled by lam_i), pivot-free 3x3 Cramer with all-positive detM,
// ONE fp64 rcp/iter (batched via w = rcp(A0*detM)), linear residuals
// carried and decayed by (1-alpha) each Newton step.
__global__ __launch_bounds__(256, 1) void lcp_kernel(
    const float* __restrict__ pv, const float* __restrict__ mu_p,
    float* __restrict__ out, int n)
{
    int i = blockIdx.x * blockDim.x + threadIdx.x;
    int half = n >> 1;
    if (i >= half) return;
    const double mu = (double)mu_p[0];

    // problems 2i and 2i+1: one coalesced float4 load
    const float4 vv = ((const float4*)pv)[i];

    double q0[2], q1[2];
    q0[0] = -(double)vv.x - 2.0;  q1[0] = -(double)vv.y + 1.0;
    q0[1] = -(double)vv.z - 2.0;  q1[1] = -(double)vv.w + 1.0;

    double z0[2], z1[2];
    double lam0[2], lam1[2], lam2[2], lam3[2];
    double s0[2], s1[2], s2[2], s3[2];
    double rd0[2], rd1[2], rp0[2], rp1[2], rp2[2], rp3[2];

    #pragma unroll
    for (int p = 0; p < 2; ++p) {
        z0[p] = -q0[p]; z1[p] = -q1[p];
        lam0[p] = lam1[p] = lam2[p] = lam3[p] = 1.0;
        s0[p] = s1[p] = s2[p] = s3[p] = 1.0;
        // initial linear residuals (carried; scaled by (1-alpha) each iter)
        rd0[p] = z0[p] + q0[p] + (lam1[p] - lam2[p]);
        rd1[p] = z1[p] + q1[p] - lam0[p];
        rp0[p] = -z1[p] + s0[p];
        rp1[p] =  z0[p] + s1[p] - lam3[p];
        rp2[p] = -z0[p] + s2[p] - lam3[p];
        rp3[p] =  s3[p] - (mu * lam0[p] - lam1[p] - lam2[p]);
    }

    for (int it = 0; it < NITER; ++it) {
        #pragma unroll
        for (int p = 0; p < 2; ++p) {
            double sl0 = s0[p]*lam0[p], sl1 = s1[p]*lam1[p];
            double sl2 = s2[p]*lam2[p], sl3 = s3[p]*lam3[p];
            double t = 0.025 * ((sl0 + sl1) + (sl2 + sl3));  // SIG*mean(s.lam)

            // scaled Schur rhs L_i = lam_i * b_i (division-free)
            double L0 = fma(lam0[p], rp0[p] + rd1[p], t - sl0);
            double L1 = fma(lam1[p], rp1[p] - rd0[p], t - sl1);
            double L2 = fma(lam2[p], rp2[p] + rd0[p], t - sl2);
            double L3 = fma(lam3[p], rp3[p],          t - sl3);

            // structural pieces (depend only on lam,s)
            double A0 = lam0[p] + s0[p];
            double a1 = lam1[p] + s1[p];
            double a2 = lam2[p] + s2[p];
            double C3 = fma(s1[p], s2[p], fma(s1[p], lam2[p], lam1[p]*s2[p]));
            double l12 = lam1[p]*lam2[p];
            double inner = fma(2.0, l12, fma(lam1[p], a2, a1*lam2[p]));
            double detM = fma(s3[p], C3, lam3[p]*inner);     // > 0, no cancel
            double K1 = fma(a2, s3[p], lam2[p]*lam3[p]);
            double K2 = fma(a1, s3[p], lam1[p]*lam3[p]);
            double e3m3 = s3[p] - lam3[p];
            double S1 = lam2[p] + a2;
            double S2 = lam1[p] + a1;
            double q1c = lam1[p] * S1;
            double q2c = lam2[p] * S2;
            double r1c = lam3[p] * S2;
            double r2c = lam3[p] * S1;

            // the single fp64 rcp of the iteration
            double w    = fast_rcp(A0 * detM);
            double idet = w * A0;        // 1/detM
            double iA0  = w * detM;      // 1/A0
            double dl0  = L0 * iA0;
            double R3   = fma(-(mu*lam3[p]), dl0, L3);

            // Cramer numerators (flat DAG)
            double N1 = fma(L1, K1, fma(lam1[p]*L2, e3m3, -(R3*q1c)));
            double N2 = fma(L2, K2, fma(lam2[p]*L1, e3m3, -(R3*q2c)));
            double N3 = fma(R3, C3, fma(L2, r1c, L1*r2c));
            double dl1 = N1*idet, dl2 = N2*idet, dl3 = N3*idet;

            // eliminated-row back-substitution
            double dz0 = -rd0[p] - dl1 + dl2;
            double dz1 = dl0 - rd1[p];

            double ds0 = dz1 - rp0[p];
            double ds1 = (dl3 - dz0) - rp1[p];
            double ds2 = (dl3 + dz0) - rp2[p];
            double ds3 = (mu*dl0 - (dl1 + dl2)) - rp3[p];

            // fraction-to-boundary: condition in fp64 (matches reference),
            // ratio in fp32 via v_rcp_f32; explicit fmin tree
            float r0 = (dl0 < -1e-12) ? ((float)lam0[p] * fast_rcpf((float)(-dl0))) : 3.0e12f;
            float r1 = (dl1 < -1e-12) ? ((float)lam1[p] * fast_rcpf((float)(-dl1))) : 3.0e12f;
            float r2 = (dl2 < -1e-12) ? ((float)lam2[p] * fast_rcpf((float)(-dl2))) : 3.0e12f;
            float r3 = (dl3 < -1e-12) ? ((float)lam3[p] * fast_rcpf((float)(-dl3))) : 3.0e12f;
            float r4 = (ds0 < -1e-12) ? ((float)s0[p] * fast_rcpf((float)(-ds0))) : 3.0e12f;
            float r5 = (ds1 < -1e-12) ? ((float)s1[p] * fast_rcpf((float)(-ds1))) : 3.0e12f;
            float r6 = (ds2 < -1e-12) ? ((float)s2[p] * fast_rcpf((float)(-ds2))) : 3.0e12f;
            float r7 = (ds3 < -1e-12) ? ((float)s3[p] * fast_rcpf((float)(-ds3))) : 3.0e12f;
            float m01 = fminf(r0, r1), m23 = fminf(r2, r3);
            float m45 = fminf(r4, r5), m67 = fminf(r6, r7);
            float amin = fminf(fminf(m01, m23), fminf(m45, m67));
            double alpha = fmin(1.0, 0.99 * (double)amin);
            double omal = 1.0 - alpha;

            z0[p] = fma(alpha, dz0, z0[p]);
            z1[p] = fma(alpha, dz1, z1[p]);
            lam0[p] = fma(alpha, dl0, lam0[p]); lam1[p] = fma(alpha, dl1, lam1[p]);
            lam2[p] = fma(alpha, dl2, lam2[p]); lam3[p] = fma(alpha, dl3, lam3[p]);
            s0[p] = fma(alpha, ds0, s0[p]); s1[p] = fma(alpha, ds1, s1[p]);
            s2[p] = fma(alpha, ds2, s2[p]); s3[p] = fma(alpha, ds3, s3[p]);

            // exact Newton decay of the linear residuals
            rd0[p] *= omal; rd1[p] *= omal;
            rp0[p] *= omal; rp1[p] *= omal; rp2[p] *= omal; rp3[p] *= omal;
        }
    }

    float4 o;
    o.x = (float)z0[0]; o.y = (float)z1[0];
    o.z = (float)z0[1]; o.w = (float)z1[1];
    ((float4*)out)[i] = o;
}

extern "C" void kernel_launch(void* const* d_in, const int* in_sizes, int n_in,
                              void* d_out, int out_size, void* d_ws, size_t ws_size,
                              hipStream_t stream) {
    const float* pv = (const float*)d_in[0];
    const float* mu = (const float*)d_in[1];
    float* out = (float*)d_out;
    int n = in_sizes[0] / 2;  // B = 131072
    int half = n >> 1;       // 2 problems per thread
    int block = 256;
    int grid = (half + block - 1) / block;
    lcp_kernel<<<grid, block, 0, stream>>>(pv, mu, out, n);
}

// Round 6
// 65.605 us; speedup vs baseline: 1.0647x; 1.0647x over previous
//
#include <hip/hip_runtime.h>

#define NITER 25

// fp64 rcp via v_rcp_f64 + 2 Newton refinements (~1 ulp).
__device__ __forceinline__ double fast_rcp(double x) {
#if __has_builtin(__builtin_amdgcn_rcp)
    double r = __builtin_amdgcn_rcp(x);
    r = fma(fma(-x, r, 1.0), r, r);
    r = fma(fma(-x, r, 1.0), r, r);
    return r;
#else
    return 1.0 / x;
#endif
}

// fp32 rcp (v_rcp_f32, ~1 ulp) — only for fraction-to-boundary ratios.
__device__ __forceinline__ float fast_rcpf(float x) {
#if __has_builtin(__builtin_amdgcn_rcpf)
    return __builtin_amdgcn_rcpf(x);
#else
    return 1.0f / x;
#endif
}

// Per-thread fp64 interior-point LCP, <=25 iterations.
//
// EXACTLY the validated R2 pipeline (passed, absmax 1.846e-3): 4x4 Schur,
// denominator-cleared (row i scaled by lam_i), pivot-free 3x3 Cramer with
// all-positive detM, ONE fp64 rcp/iter, linear residuals carried and
// decayed by (1-alpha).
//
// ONLY change this round: wave-uniform EARLY BREAK. sigma=0.1 contracts
// mu_c ~10x/iter once alpha~1; when every lane in the wave has
// t = SIG*mu_c < 1e-11, all remaining iterations move z by O(mu_c)~1e-10
// total — invisible vs the 1.8e-3 fp32-reference noise (threshold 2.7e-1).
// Every executed iteration is bit-identical to the R2 kernel; fp64
// deep-iteration through full 25 iters is already measurement-proven safe
// (R1-R3), so no freeze/guard logic is needed. fp32 port abandoned for now:
// two unexplained NaN failures (R4/R5) — mechanism unidentified, reverted.
__global__ __launch_bounds__(256) void lcp_kernel(
    const float* __restrict__ pv, const float* __restrict__ mu_p,
    float* __restrict__ out, int n)
{
    int i = blockIdx.x * blockDim.x + threadIdx.x;
    if (i >= n) return;
    const double mu = (double)mu_p[0];

    const float2 v = ((const float2*)pv)[i];
    const double q0 = -(double)v.x - 2.0;   // q = -v + (-2, 1), MASS=1
    const double q1 = -(double)v.y + 1.0;

    double z0 = -q0, z1 = -q1;
    double lam0 = 1.0, lam1 = 1.0, lam2 = 1.0, lam3 = 1.0;
    double s0 = 1.0, s1 = 1.0, s2 = 1.0, s3 = 1.0;

    // initial linear residuals at z=-q, lam=s=1 (closed forms, exact):
    // rd0 = z0+q0+(lam1-lam2) = 0; rd1 = z1+q1-lam0 = -1;
    // rp0 = 1-z1; rp1 = z0; rp2 = -z0; rp3 = 3-mu.
    double rd0 = 0.0;
    double rd1 = -1.0;
    double rp0 = 1.0 - z1;
    double rp1 = z0;
    double rp2 = -z0;
    double rp3 = 3.0 - mu;

    for (int it = 0; it < NITER; ++it) {
        double sl0 = s0*lam0, sl1 = s1*lam1, sl2 = s2*lam2, sl3 = s3*lam3;
        double t = 0.025 * ((sl0 + sl1) + (sl2 + sl3));   // SIG * mean(s.lam)

        // scaled Schur rhs L_i = lam_i * b_i (division-free)
        double L0 = fma(lam0, rp0 + rd1, t - sl0);
        double L1 = fma(lam1, rp1 - rd0, t - sl1);
        double L2 = fma(lam2, rp2 + rd0, t - sl2);
        double L3 = fma(lam3, rp3,       t - sl3);

        // scaled-system structural pieces (depend only on lam,s)
        double A0 = lam0 + s0;
        double a1 = lam1 + s1;
        double a2 = lam2 + s2;
        double C3 = fma(s1, s2, fma(s1, lam2, lam1*s2));     // a1*a2 - lam1*lam2
        double inner = fma(2.0, lam1*lam2, fma(lam1, a2, a1*lam2));
        double detM = fma(s3, C3, lam3*inner);               // > 0, no cancellation
        double K1 = fma(a2, s3, lam2*lam3);
        double K2 = fma(a1, s3, lam1*lam3);
        double e3m3 = s3 - lam3;
        double S1 = lam2 + a2;       // m2 + a2
        double S2 = lam1 + a1;       // m1 + a1
        double q1c = lam1 * S1;
        double q2c = lam2 * S2;
        double r1c = lam3 * S2;
        double r2c = lam3 * S1;

        // the single fp64 rcp of the iteration
        double w    = fast_rcp(A0 * detM);
        double idet = w * A0;        // 1/detM
        double iA0  = w * detM;      // 1/A0
        double dl0  = L0 * iA0;
        double R3   = fma(-(mu*lam3), dl0, L3);

        // Cramer numerators (flat DAG)
        double N1 = fma(L1, K1, fma(lam1*L2, e3m3, -(R3*q1c)));
        double N2 = fma(L2, K2, fma(lam2*L1, e3m3, -(R3*q2c)));
        double N3 = fma(R3, C3, fma(L2, r1c, L1*r2c));
        double dl1 = N1*idet, dl2 = N2*idet, dl3 = N3*idet;

        // eliminated-row back-substitution
        double dz0 = -rd0 - dl1 + dl2;
        double dz1 = dl0 - rd1;

        double ds0 = dz1 - rp0;
        double ds1 = (dl3 - dz0) - rp1;
        double ds2 = (dl3 + dz0) - rp2;
        double ds3 = (mu*dl0 - (dl1 + dl2)) - rp3;

        // fraction-to-boundary: condition in fp64 (matches reference),
        // ratio in fp32 via v_rcp_f32; explicit fmin tree
        float r0 = (dl0 < -1e-12) ? ((float)lam0 * fast_rcpf((float)(-dl0))) : 3.0e12f;
        float r1 = (dl1 < -1e-12) ? ((float)lam1 * fast_rcpf((float)(-dl1))) : 3.0e12f;
        float r2 = (dl2 < -1e-12) ? ((float)lam2 * fast_rcpf((float)(-dl2))) : 3.0e12f;
        float r3 = (dl3 < -1e-12) ? ((float)lam3 * fast_rcpf((float)(-dl3))) : 3.0e12f;
        float r4 = (ds0 < -1e-12) ? ((float)s0 * fast_rcpf((float)(-ds0))) : 3.0e12f;
        float r5 = (ds1 < -1e-12) ? ((float)s1 * fast_rcpf((float)(-ds1))) : 3.0e12f;
        float r6 = (ds2 < -1e-12) ? ((float)s2 * fast_rcpf((float)(-ds2))) : 3.0e12f;
        float r7 = (ds3 < -1e-12) ? ((float)s3 * fast_rcpf((float)(-ds3))) : 3.0e12f;
        float m01 = fminf(r0, r1), m23 = fminf(r2, r3);
        float m45 = fminf(r4, r5), m67 = fminf(r6, r7);
        float amin = fminf(fminf(m01, m23), fminf(m45, m67));
        double alpha = fmin(1.0, 0.99 * (double)amin);
        double omal = 1.0 - alpha;

        z0 = fma(alpha, dz0, z0);
        z1 = fma(alpha, dz1, z1);
        lam0 = fma(alpha, dl0, lam0); lam1 = fma(alpha, dl1, lam1);
        lam2 = fma(alpha, dl2, lam2); lam3 = fma(alpha, dl3, lam3);
        s0 = fma(alpha, ds0, s0); s1 = fma(alpha, ds1, s1);
        s2 = fma(alpha, ds2, s2); s3 = fma(alpha, ds3, s3);

        // exact Newton decay of the linear residuals
        rd0 *= omal; rd1 *= omal;
        rp0 *= omal; rp1 *= omal; rp2 *= omal; rp3 *= omal;

        // wave-uniform early break: all 64 lanes converged (t = SIG*mu_c
        // measured pre-step; remaining z-drift O(1e-10) << 1.8e-3 noise)
        if (__all(t < 1e-11)) break;
    }

    ((float2*)out)[i] = make_float2((float)z0, (float)z1);
}

extern "C" void kernel_launch(void* const* d_in, const int* in_sizes, int n_in,
                              void* d_out, int out_size, void* d_ws, size_t ws_size,
                              hipStream_t stream) {
    const float* pv = (const float*)d_in[0];
    const float* mu = (const float*)d_in[1];
    float* out = (float*)d_out;
    int n = in_sizes[0] / 2;  // B = 131072
    int block = 256;
    int grid = (n + block - 1) / block;
    lcp_kernel<<<grid, block, 0, stream>>>(pv, mu, out, n);
}

// Round 9
// 54.244 us; speedup vs baseline: 1.2877x; 1.2094x over previous
//
#include <hip/hip_runtime.h>

// Closed-form solution of the reference's LCP.
//
// The reference's 25-iteration interior-point method solves, per lane, the
// KKT/complementarity system (derived from its own residual definitions):
//     z = -q - G^T lam,   s = F lam - G z,   0 <= lam  _|_  s >= 0
// with q = (-vx-2, -vy+1), G rows (0,-1),(1,0),(-1,0),(0,0), and
// F = [[0,0,0,0],[0,0,0,1],[0,0,0,1],[mu,-1,-1,0]].
// Componentwise:
//     z0 = -q0 - lam1 + lam2        z1 = -q1 + lam0
//     s0 = z1        (normal gap)       lam0 = normal impulse
//     s1 = lam3 - z0, s2 = lam3 + z0   (friction rows; lam3 >= |z0|)
//     s3 = mu*lam0 - lam1 - lam2       (friction cone)
// This is the standard 2D frictional-contact LCP. Case analysis (z is
// UNIQUE and continuous; lam may be non-unique in stick but z ignores it):
//   separation (q1 <= 0):  lam = 0,  z = (-q0, -q1)
//   contact    (q1 > 0):   lam0 = q1, z1 = 0, and with t0 = -q0, mq = mu*q1:
//       stick  |t0| <= mq : z0 = 0
//       slide   t0  >  mq : lam1 = mq (cone-saturated), z0 = t0 - mq
//       slide   t0  < -mq : lam2 = mq,                  z0 = t0 + mq
//   (i.e. z0 = soft-threshold(t0, mq))
//
// Validation of "IP(25) ~= exact": our fully-converged fp64 IP (R6, passed)
// matched the harness's np reference to absmax 1.846e-3 on all 131072 lanes;
// the exact solution is the common limit of both. Threshold is 2.7e-1 —
// ~150x headroom. fp32-trajectory replication was abandoned after R4/R5/R7/
// R8 (chaotic sensitivity of the iteration, not fixable by guards).
//
// Perf: ~10 fp32 ops/lane; pure streaming (1 MB in, 1 MB out) — kernel is
// at the HBM/launch floor; total dur sits on the harness's 40 us fill.
__global__ __launch_bounds__(256) void lcp_kernel(
    const float* __restrict__ pv, const float* __restrict__ mu_p,
    float* __restrict__ out, int half)
{
    int i = blockIdx.x * blockDim.x + threadIdx.x;
    if (i >= half) return;
    const float mu = mu_p[0];

    // two problems per thread: one coalesced float4 load/store
    const float4 vv = ((const float4*)pv)[i];
    float4 o;

    // ---- problem 0: v = (vv.x, vv.y) ----
    {
        const float q0 = -vv.x - 2.0f;
        const float q1 = -vv.y + 1.0f;
        const float t0 = -q0;                 // = vx + 2
        const float mq = mu * q1;
        // contact: soft-threshold; separation: free velocity
        float zc = (t0 > mq) ? (t0 - mq) : ((t0 < -mq) ? (t0 + mq) : 0.0f);
        bool contact = (q1 > 0.0f);
        o.x = contact ? zc : t0;
        o.y = contact ? 0.0f : -q1;
    }

    // ---- problem 1: v = (vv.z, vv.w) ----
    {
        const float q0 = -vv.z - 2.0f;
        const float q1 = -vv.w + 1.0f;
        const float t0 = -q0;
        const float mq = mu * q1;
        float zc = (t0 > mq) ? (t0 - mq) : ((t0 < -mq) ? (t0 + mq) : 0.0f);
        bool contact = (q1 > 0.0f);
        o.z = contact ? zc : t0;
        o.w = contact ? 0.0f : -q1;
    }

    ((float4*)out)[i] = o;
}

extern "C" void kernel_launch(void* const* d_in, const int* in_sizes, int n_in,
                              void* d_out, int out_size, void* d_ws, size_t ws_size,
                              hipStream_t stream) {
    const float* pv = (const float*)d_in[0];
    const float* mu = (const float*)d_in[1];
    float* out = (float*)d_out;
    int n = in_sizes[0] / 2;  // B = 131072
    int half = n >> 1;        // 2 problems per thread (float4 path)
    int block = 256;
    int grid = (half + block - 1) / block;
    lcp_kernel<<<grid, block, 0, stream>>>(pv, mu, out, half);
}